// Round 1
// baseline (712.625 us; speedup 1.0000x reference)
//
#include <hip/hip_runtime.h>

// ActorCritic fused kernel: LSTM scan (B=1024,T=256,F=128,H=128) + MLP heads.
// 64 blocks x 512 threads; block owns 16 batch rows; weights resident in VGPRs
// as fp16 MFMA B-fragments; A operand double-buffered in LDS in fragment order.

typedef _Float16 f16x8 __attribute__((ext_vector_type(8)));
typedef _Float16 f16x4 __attribute__((ext_vector_type(4)));
typedef float    f32x4 __attribute__((ext_vector_type(4)));

__device__ __forceinline__ float fast_sigmoid(float x) {
    return 1.0f / (1.0f + __expf(-x));
}
__device__ __forceinline__ float fast_tanh(float x) {
    return 2.0f * fast_sigmoid(2.0f * x) - 1.0f;
}

__global__ __launch_bounds__(512, 2)
void ac_fused(const float* __restrict__ hin,
              const float* __restrict__ Wx, const float* __restrict__ Wh,
              const float* __restrict__ bh,
              const float* __restrict__ Wa1, const float* __restrict__ ba1,
              const float* __restrict__ Wa2, const float* __restrict__ ba2,
              const float* __restrict__ Wa3, const float* __restrict__ ba3,
              const float* __restrict__ logstd,
              const float* __restrict__ Wc1, const float* __restrict__ bc1,
              const float* __restrict__ Wc2, const float* __restrict__ bc2,
              const float* __restrict__ Wc3, const float* __restrict__ bc3,
              float* __restrict__ out)
{
    constexpr int T = 256, F = 128, H = 128, G = 512; // G = 4*H

    // A staging in MFMA fragment order: chunk = kt*64 + quad*16 + m holds
    // A[m][k], k = kt*32 + quad*8 + j  (j = index inside the f16x8 chunk).
    __shared__ f16x8 Abuf[2][512];          // 2 x 8 KB
    __shared__ float xf[16][F + 1];         // final hidden (fp32)
    __shared__ float hb[2][16][257];        // head layer ping-pong

    const int tid  = threadIdx.x;
    const int lane = tid & 63;
    const int wv   = tid >> 6;    // wave 0..7
    const int m16  = lane & 15;
    const int q    = lane >> 4;   // quad 0..3
    const int r0   = blockIdx.x << 4;

    // ---- load weight B-fragments into registers ----
    // wave wv covers column (s*128 + wv*16 + m16) in each gate section s
    f16x8 bw[4][8];
    const int ncol = (wv << 4) + m16;
    #pragma unroll
    for (int kt = 0; kt < 8; ++kt) {
        #pragma unroll
        for (int s = 0; s < 4; ++s) {
            f16x8 v;
            #pragma unroll
            for (int j = 0; j < 8; ++j) {
                const int k = (kt << 5) + (q << 3) + j;   // 0..255
                const float w = (k < F) ? Wx[k * G + s * H + ncol]
                                        : Wh[(k - F) * G + s * H + ncol];
                v[j] = (_Float16)w;
            }
            bw[s][kt] = v;
        }
    }
    float bias[4];
    #pragma unroll
    for (int s = 0; s < 4; ++s) bias[s] = bh[s * H + ncol];

    // ---- stage x_0 and h_0 = 0 into Abuf[0] ----
    const int lrow = tid >> 5;   // 0..15
    const int lseg = tid & 31;   // 0..31
    {
        const float4 x0 = *(const float4*)(hin + ((size_t)(r0 + lrow) * T + 0) * F + (lseg << 2));
        const int k0 = lseg << 2;
        f16x4 p; p[0] = (_Float16)x0.x; p[1] = (_Float16)x0.y;
                 p[2] = (_Float16)x0.z; p[3] = (_Float16)x0.w;
        _Float16* dst = (_Float16*)&Abuf[0][((k0 >> 5) << 6) + (((k0 >> 3) & 3) << 4) + lrow] + (k0 & 7);
        *(f16x4*)dst = p;
        f16x4 zz = {};
        *(f16x4*)((_Float16*)&Abuf[0][256 + (tid >> 1)] + ((tid & 1) << 2)) = zz;
    }

    f32x4 cst = {0.f, 0.f, 0.f, 0.f};   // cell state: rows q*4+g, dim dimc
    f32x4 hlast;
    const int dimc = (wv << 4) + m16;   // this lane's h-dim (0..127)
    const int kk   = F + dimc;          // position of h in combined K
    const int hchunk = ((kk >> 5) << 6) + (((kk >> 3) & 3) << 4);
    const int jn   = kk & 7;

    __syncthreads();

    for (int t = 0; t < T; ++t) {
        // prefetch x_{t+1} (latency hidden under MFMA)
        const int tp = (t + 1 < T) ? t + 1 : T - 1;
        const float4 xn = *(const float4*)(hin + ((size_t)(r0 + lrow) * T + tp) * F + (lseg << 2));

        // ---- MFMA: z = [x_t, h] @ W + b ----
        const f16x8* Ab = &Abuf[t & 1][0];
        f32x4 z0 = {bias[0], bias[0], bias[0], bias[0]};
        f32x4 z1 = {bias[1], bias[1], bias[1], bias[1]};
        f32x4 z2 = {bias[2], bias[2], bias[2], bias[2]};
        f32x4 z3 = {bias[3], bias[3], bias[3], bias[3]};
        #pragma unroll
        for (int kt = 0; kt < 8; ++kt) {
            const f16x8 a = Ab[(kt << 6) + lane];
            z0 = __builtin_amdgcn_mfma_f32_16x16x32_f16(a, bw[0][kt], z0, 0, 0, 0);
            z1 = __builtin_amdgcn_mfma_f32_16x16x32_f16(a, bw[1][kt], z1, 0, 0, 0);
            z2 = __builtin_amdgcn_mfma_f32_16x16x32_f16(a, bw[2][kt], z2, 0, 0, 0);
            z3 = __builtin_amdgcn_mfma_f32_16x16x32_f16(a, bw[3][kt], z3, 0, 0, 0);
        }

        // ---- cell update, fully in-register (i,f,g,o all local to the lane) ----
        _Float16* An = (_Float16*)&Abuf[(t + 1) & 1][0];
        #pragma unroll
        for (int g = 0; g < 4; ++g) {
            const float iv = fast_sigmoid(z0[g]);
            const float fv = fast_sigmoid(z1[g]);
            const float gv = fast_tanh(z2[g]);
            const float ov = fast_sigmoid(z3[g]);
            const float cn = fv * cst[g] + iv * gv;
            cst[g] = cn;
            const float hv = ov * fast_tanh(cn);
            hlast[g] = hv;
            An[(hchunk + (q << 2) + g) * 8 + jn] = (_Float16)hv;
        }

        // ---- store prefetched x_{t+1} into next buffer ----
        {
            const int k0 = lseg << 2;
            f16x4 p; p[0] = (_Float16)xn.x; p[1] = (_Float16)xn.y;
                     p[2] = (_Float16)xn.z; p[3] = (_Float16)xn.w;
            _Float16* dst = An + (((k0 >> 5) << 6) + (((k0 >> 3) & 3) << 4) + lrow) * 8 + (k0 & 7);
            *(f16x4*)dst = p;
        }
        __syncthreads();
    }

    // ---- final hidden (fp32, pre-rounding) to LDS for the heads ----
    #pragma unroll
    for (int g = 0; g < 4; ++g) xf[(q << 2) + g][dimc] = hlast[g];
    __syncthreads();

    // ---- MLP heads (fp32 VALU; tiny FLOPs) ----
    const int n  = tid & 255;
    const int rh = tid >> 8;

    auto layer = [&](const float* __restrict__ W, const float* __restrict__ bv,
                     const float* xin, int xs, int K, float* yout, int ys) {
        float acc[8];
        const float b = bv[n];
        #pragma unroll
        for (int r = 0; r < 8; ++r) acc[r] = b;
        for (int k = 0; k < K; ++k) {
            const float w = W[k * 256 + n];
            #pragma unroll
            for (int r = 0; r < 8; ++r) acc[r] += xin[(rh * 8 + r) * xs + k] * w;
        }
        #pragma unroll
        for (int r = 0; r < 8; ++r) yout[(rh * 8 + r) * ys + n] = fast_tanh(acc[r]);
    };

    layer(Wa1, ba1, &xf[0][0], F + 1, 128, &hb[0][0][0], 257);   // actor L1
    __syncthreads();
    layer(Wa2, ba2, &hb[0][0][0], 257, 256, &hb[1][0][0], 257);  // actor L2
    __syncthreads();
    layer(Wc1, bc1, &xf[0][0], F + 1, 128, &hb[0][0][0], 257);   // critic L1
    if (tid < 128) {                                             // actor L3: mean + std
        const int r = tid >> 3, a = tid & 7;
        float acc = ba3[a];
        for (int k = 0; k < 256; ++k) acc += hb[1][r][k] * Wa3[k * 8 + a];
        out[(size_t)(r0 + r) * 17 + a]     = acc;
        out[(size_t)(r0 + r) * 17 + 8 + a] = __expf(logstd[a]);
    }
    __syncthreads();
    layer(Wc2, bc2, &hb[0][0][0], 257, 256, &hb[1][0][0], 257);  // critic L2
    __syncthreads();
    if (tid < 16) {                                              // critic L3: value
        const int r = tid;
        float acc = bc3[0];
        for (int k = 0; k < 256; ++k) acc += hb[1][r][k] * Wc3[k];
        out[(size_t)(r0 + r) * 17 + 16] = acc;
    }
}

extern "C" void kernel_launch(void* const* d_in, const int* in_sizes, int n_in,
                              void* d_out, int out_size, void* d_ws, size_t ws_size,
                              hipStream_t stream) {
    (void)in_sizes; (void)n_in; (void)d_ws; (void)ws_size; (void)out_size;
    const float* hin = (const float*)d_in[0];
    const float* Wx  = (const float*)d_in[1];
    const float* Wh  = (const float*)d_in[2];
    const float* bh  = (const float*)d_in[3];
    const float* Wa1 = (const float*)d_in[4];
    const float* ba1 = (const float*)d_in[5];
    const float* Wa2 = (const float*)d_in[6];
    const float* ba2 = (const float*)d_in[7];
    const float* Wa3 = (const float*)d_in[8];
    const float* ba3 = (const float*)d_in[9];
    const float* ls  = (const float*)d_in[10];
    const float* Wc1 = (const float*)d_in[11];
    const float* bc1 = (const float*)d_in[12];
    const float* Wc2 = (const float*)d_in[13];
    const float* bc2 = (const float*)d_in[14];
    const float* Wc3 = (const float*)d_in[15];
    const float* bc3 = (const float*)d_in[16];

    hipLaunchKernelGGL(ac_fused, dim3(64), dim3(512), 0, stream,
                       hin, Wx, Wh, bh, Wa1, ba1, Wa2, ba2, Wa3, ba3, ls,
                       Wc1, bc1, Wc2, bc2, Wc3, bc3, (float*)d_out);
}

// Round 2
// 612.253 us; speedup vs baseline: 1.1639x; 1.1639x over previous
//
#include <hip/hip_runtime.h>

// ActorCritic fused kernel: LSTM scan (B=1024,T=256,F=128,H=128) + MLP heads.
// 64 blocks x 512 threads; block owns 16 batch rows; weights resident in VGPRs/AGPRs
// as fp16 MFMA B-fragments; A operand double-buffered in LDS in fragment order.
// R2: rcp-based activations (no IEEE div), packed b32 h-writes, chunk-linear x staging.

typedef _Float16 f16x8 __attribute__((ext_vector_type(8)));
typedef _Float16 f16x4 __attribute__((ext_vector_type(4)));
typedef _Float16 f16x2 __attribute__((ext_vector_type(2)));
typedef float    f32x4 __attribute__((ext_vector_type(4)));

#define NLOG2E (-1.4426950408889634f)

__device__ __forceinline__ float rcpf(float x) { return __builtin_amdgcn_rcpf(x); }

__global__ __launch_bounds__(512, 2)
void ac_fused(const float* __restrict__ hin,
              const float* __restrict__ Wx, const float* __restrict__ Wh,
              const float* __restrict__ bh,
              const float* __restrict__ Wa1, const float* __restrict__ ba1,
              const float* __restrict__ Wa2, const float* __restrict__ ba2,
              const float* __restrict__ Wa3, const float* __restrict__ ba3,
              const float* __restrict__ logstd,
              const float* __restrict__ Wc1, const float* __restrict__ bc1,
              const float* __restrict__ Wc2, const float* __restrict__ bc2,
              const float* __restrict__ Wc3, const float* __restrict__ bc3,
              float* __restrict__ out)
{
    constexpr int T = 256, F = 128, H = 128, G = 512; // G = 4*H

    // A staging in MFMA fragment order: chunk = kt*64 + quad*16 + m holds
    // A[m][k], k = kt*32 + quad*8 + j  (j = index inside the f16x8 chunk).
    __shared__ f16x8 Abuf[2][512];          // 2 x 8 KB
    __shared__ float xf[16][F + 1];         // final hidden (fp32)
    __shared__ float hb[2][16][257];        // head layer ping-pong

    const int tid  = threadIdx.x;
    const int lane = tid & 63;
    const int wv   = tid >> 6;    // wave 0..7
    const int m16  = lane & 15;
    const int q    = lane >> 4;   // quad 0..3
    const int p    = lane & 1;    // pair parity
    const int r0   = blockIdx.x << 4;

    // ---- load weight B-fragments into registers ----
    // wave wv covers column (s*128 + wv*16 + m16) in each gate section s
    f16x8 bw[4][8];
    const int ncol = (wv << 4) + m16;
    #pragma unroll
    for (int kt = 0; kt < 8; ++kt) {
        #pragma unroll
        for (int s = 0; s < 4; ++s) {
            f16x8 v;
            #pragma unroll
            for (int j = 0; j < 8; ++j) {
                const int k = (kt << 5) + (q << 3) + j;   // 0..255
                const float w = (k < F) ? Wx[k * G + s * H + ncol]
                                        : Wh[(k - F) * G + s * H + ncol];
                v[j] = (_Float16)w;
            }
            bw[s][kt] = v;
        }
    }
    // bias folded into the exp2 argument:  sig(z+b) = rcp(1 + 2^(z*NLOG2E + nb))
    const float nbi = NLOG2E * bh[0 * H + ncol];
    const float nbf = NLOG2E * bh[1 * H + ncol];
    const float nbg = 2.0f * NLOG2E * bh[2 * H + ncol];
    const float nbo = NLOG2E * bh[3 * H + ncol];

    // ---- x staging: thread stages half-chunk (chunk = tid>>1, half = tid&1) ----
    const int xc = tid >> 1;              // chunk 0..255 (x half of K)
    const int xh = tid & 1;               // which f16x4 inside the chunk
    const int xm = xc & 15;               // batch row
    const int xk0 = ((xc >> 6) << 5) + (((xc >> 4) & 3) << 3) + (xh << 2); // k 0..124
    const float* pxbase = hin + (size_t)(r0 + xm) * T * F + xk0;

    // h-write indices (dword units into Abuf): lane pair (2a,2a+1) shares dwords.
    const int dimc = (wv << 4) + m16;     // this lane's h-dim (0..127)
    const int kk   = F + dimc;            // position of h in combined K
    const int hchunk = ((kk >> 5) << 6) + (((kk >> 3) & 3) << 4);
    const int a    = (m16 & 7) >> 1;      // dword inside chunk
    const int widx0 = (hchunk + (q << 2) + (p << 1)) * 4 + a;
    const int widx1 = widx0 + 4;

    // ---- stage x_0 and h_0 = 0 into Abuf[0] ----
    {
        const float4 x0 = *(const float4*)pxbase;
        f16x4 pk;
        pk[0] = (_Float16)x0.x; pk[1] = (_Float16)x0.y;
        pk[2] = (_Float16)x0.z; pk[3] = (_Float16)x0.w;
        *(f16x4*)((_Float16*)&Abuf[0][0] + xc * 8 + xh * 4) = pk;
        f16x4 zz = {};
        *(f16x4*)((_Float16*)&Abuf[0][0] + (256 + xc) * 8 + xh * 4) = zz;
    }

    f32x4 cst = {0.f, 0.f, 0.f, 0.f};   // cell state: rows q*4+g, dim dimc
    f32x4 hlast;

    __syncthreads();

    for (int t = 0; t < T; ++t) {
        // prefetch x_{t+1} (latency hidden under MFMA)
        const int tp = (t + 1 < T) ? t + 1 : T - 1;
        const float4 xn = *(const float4*)(pxbase + (size_t)tp * F);

        // ---- MFMA: z = [x_t, h] @ W  (bias folded into activation) ----
        const f16x8* Ab = &Abuf[t & 1][0];
        f32x4 z0 = {0.f, 0.f, 0.f, 0.f};
        f32x4 z1 = {0.f, 0.f, 0.f, 0.f};
        f32x4 z2 = {0.f, 0.f, 0.f, 0.f};
        f32x4 z3 = {0.f, 0.f, 0.f, 0.f};
        #pragma unroll
        for (int kt = 0; kt < 8; ++kt) {
            const f16x8 af = Ab[(kt << 6) + lane];
            z0 = __builtin_amdgcn_mfma_f32_16x16x32_f16(af, bw[0][kt], z0, 0, 0, 0);
            z1 = __builtin_amdgcn_mfma_f32_16x16x32_f16(af, bw[1][kt], z1, 0, 0, 0);
            z2 = __builtin_amdgcn_mfma_f32_16x16x32_f16(af, bw[2][kt], z2, 0, 0, 0);
            z3 = __builtin_amdgcn_mfma_f32_16x16x32_f16(af, bw[3][kt], z3, 0, 0, 0);
        }

        // ---- cell update, fully in-register (i,f,g,o all local to the lane) ----
        #pragma unroll
        for (int g = 0; g < 4; ++g) {
            const float iv = rcpf(1.0f + exp2f(fmaf(z0[g], NLOG2E, nbi)));
            const float fv = rcpf(1.0f + exp2f(fmaf(z1[g], NLOG2E, nbf)));
            const float gv = 2.0f * rcpf(1.0f + exp2f(fmaf(z2[g], 2.0f * NLOG2E, nbg))) - 1.0f;
            const float ov = rcpf(1.0f + exp2f(fmaf(z3[g], NLOG2E, nbo)));
            const float cn = fv * cst[g] + iv * gv;
            cst[g] = cn;
            const float th = 2.0f * rcpf(1.0f + exp2f(cn * (2.0f * NLOG2E))) - 1.0f;
            hlast[g] = ov * th;
        }

        // ---- pack h with pair lane (via shfl_xor) -> 2x b32 writes ----
        uint32_t* An32 = (uint32_t*)&Abuf[(t + 1) & 1][0];
        uint32_t dd[4];
        #pragma unroll
        for (int g = 0; g < 4; ++g) {
            const float pp = __shfl_xor(hlast[g], 1);
            const float lo = p ? pp : hlast[g];
            const float hi = p ? hlast[g] : pp;
            dd[g] = __builtin_bit_cast(uint32_t, __builtin_amdgcn_cvt_pkrtz(lo, hi));
        }
        An32[widx0] = p ? dd[2] : dd[0];
        An32[widx1] = p ? dd[3] : dd[1];

        // ---- store prefetched x_{t+1} (chunk-linear, conflict-free b64) ----
        {
            f16x4 pk;
            pk[0] = (_Float16)xn.x; pk[1] = (_Float16)xn.y;
            pk[2] = (_Float16)xn.z; pk[3] = (_Float16)xn.w;
            *(f16x4*)((_Float16*)An32 + xc * 8 + xh * 4) = pk;
        }
        __syncthreads();
    }

    // ---- final hidden (fp32, pre-rounding) to LDS for the heads ----
    #pragma unroll
    for (int g = 0; g < 4; ++g) xf[(q << 2) + g][dimc] = hlast[g];
    __syncthreads();

    // ---- MLP heads (fp32 VALU; tiny FLOPs) ----
    const int n  = tid & 255;
    const int rh = tid >> 8;

    auto sigl = [&](float x) { return rcpf(1.0f + exp2f(x * NLOG2E)); };
    auto tanhl = [&](float x) { return 2.0f * rcpf(1.0f + exp2f(x * (2.0f * NLOG2E))) - 1.0f; };

    auto layer = [&](const float* __restrict__ W, const float* __restrict__ bv,
                     const float* xin, int xs, int K, float* yout, int ys) {
        float acc[8];
        const float b = bv[n];
        #pragma unroll
        for (int r = 0; r < 8; ++r) acc[r] = b;
        for (int k = 0; k < K; ++k) {
            const float w = W[k * 256 + n];
            #pragma unroll
            for (int r = 0; r < 8; ++r) acc[r] += xin[(rh * 8 + r) * xs + k] * w;
        }
        #pragma unroll
        for (int r = 0; r < 8; ++r) yout[(rh * 8 + r) * ys + n] = tanhl(acc[r]);
    };

    layer(Wa1, ba1, &xf[0][0], F + 1, 128, &hb[0][0][0], 257);   // actor L1
    __syncthreads();
    layer(Wa2, ba2, &hb[0][0][0], 257, 256, &hb[1][0][0], 257);  // actor L2
    __syncthreads();
    layer(Wc1, bc1, &xf[0][0], F + 1, 128, &hb[0][0][0], 257);   // critic L1
    if (tid < 128) {                                             // actor L3: mean + std
        const int r = tid >> 3, aa = tid & 7;
        float acc = ba3[aa];
        for (int k = 0; k < 256; ++k) acc += hb[1][r][k] * Wa3[k * 8 + aa];
        out[(size_t)(r0 + r) * 17 + aa]     = acc;
        out[(size_t)(r0 + r) * 17 + 8 + aa] = __expf(logstd[aa]);
    }
    __syncthreads();
    layer(Wc2, bc2, &hb[0][0][0], 257, 256, &hb[1][0][0], 257);  // critic L2
    __syncthreads();
    if (tid < 16) {                                              // critic L3: value
        const int r = tid;
        float acc = bc3[0];
        for (int k = 0; k < 256; ++k) acc += hb[1][r][k] * Wc3[k];
        out[(size_t)(r0 + r) * 17 + 16] = acc;
    }
}

extern "C" void kernel_launch(void* const* d_in, const int* in_sizes, int n_in,
                              void* d_out, int out_size, void* d_ws, size_t ws_size,
                              hipStream_t stream) {
    (void)in_sizes; (void)n_in; (void)d_ws; (void)ws_size; (void)out_size;
    const float* hin = (const float*)d_in[0];
    const float* Wx  = (const float*)d_in[1];
    const float* Wh  = (const float*)d_in[2];
    const float* bh  = (const float*)d_in[3];
    const float* Wa1 = (const float*)d_in[4];
    const float* ba1 = (const float*)d_in[5];
    const float* Wa2 = (const float*)d_in[6];
    const float* ba2 = (const float*)d_in[7];
    const float* Wa3 = (const float*)d_in[8];
    const float* ba3 = (const float*)d_in[9];
    const float* ls  = (const float*)d_in[10];
    const float* Wc1 = (const float*)d_in[11];
    const float* bc1 = (const float*)d_in[12];
    const float* Wc2 = (const float*)d_in[13];
    const float* bc2 = (const float*)d_in[14];
    const float* Wc3 = (const float*)d_in[15];
    const float* bc3 = (const float*)d_in[16];

    hipLaunchKernelGGL(ac_fused, dim3(64), dim3(512), 0, stream,
                       hin, Wx, Wh, bh, Wa1, ba1, Wa2, ba2, Wa3, ba3, ls,
                       Wc1, bc1, Wc2, bc2, Wc3, bc3, (float*)d_out);
}

// Round 3
// 570.315 us; speedup vs baseline: 1.2495x; 1.0735x over previous
//
#include <hip/hip_runtime.h>

// ActorCritic fused kernel: LSTM scan (B=1024,T=256,F=128,H=128) + MLP heads.
// 64 blocks x 512 threads; block owns 16 batch rows; weights resident in VGPRs/AGPRs
// as fp16 MFMA B-fragments; A operand double-buffered in LDS in fragment order.
// R2: rcp-based activations, packed b32 h-writes, chunk-linear x staging.
// R3: raw v_exp_f32 intrinsic (no OCML wrapper), DPP pair-swap instead of shfl,
//     unrolled head loops.

typedef _Float16 f16x8 __attribute__((ext_vector_type(8)));
typedef _Float16 f16x4 __attribute__((ext_vector_type(4)));
typedef float    f32x4 __attribute__((ext_vector_type(4)));

#define NLOG2E (-1.4426950408889634f)

__device__ __forceinline__ float rcpf(float x) { return __builtin_amdgcn_rcpf(x); }
__device__ __forceinline__ float ex2(float x)  { return __builtin_amdgcn_exp2f(x); }
// swap adjacent lanes (1<->0, 3<->2, ...): quad_perm [1,0,3,2] = 0xB1
__device__ __forceinline__ float dpp_swap1(float x) {
    return __builtin_bit_cast(float,
        __builtin_amdgcn_mov_dpp(__builtin_bit_cast(int, x), 0xB1, 0xF, 0xF, true));
}

__global__ __launch_bounds__(512, 2)
void ac_fused(const float* __restrict__ hin,
              const float* __restrict__ Wx, const float* __restrict__ Wh,
              const float* __restrict__ bh,
              const float* __restrict__ Wa1, const float* __restrict__ ba1,
              const float* __restrict__ Wa2, const float* __restrict__ ba2,
              const float* __restrict__ Wa3, const float* __restrict__ ba3,
              const float* __restrict__ logstd,
              const float* __restrict__ Wc1, const float* __restrict__ bc1,
              const float* __restrict__ Wc2, const float* __restrict__ bc2,
              const float* __restrict__ Wc3, const float* __restrict__ bc3,
              float* __restrict__ out)
{
    constexpr int T = 256, F = 128, H = 128, G = 512; // G = 4*H

    // A staging in MFMA fragment order: chunk = kt*64 + quad*16 + m holds
    // A[m][k], k = kt*32 + quad*8 + j  (j = index inside the f16x8 chunk).
    __shared__ f16x8 Abuf[2][512];          // 2 x 8 KB
    __shared__ float xf[16][F + 1];         // final hidden (fp32)
    __shared__ float hb[2][16][257];        // head layer ping-pong

    const int tid  = threadIdx.x;
    const int lane = tid & 63;
    const int wv   = tid >> 6;    // wave 0..7
    const int m16  = lane & 15;
    const int q    = lane >> 4;   // quad 0..3
    const int p    = lane & 1;    // pair parity
    const int r0   = blockIdx.x << 4;

    // ---- load weight B-fragments into registers ----
    // wave wv covers column (s*128 + wv*16 + m16) in each gate section s
    f16x8 bw[4][8];
    const int ncol = (wv << 4) + m16;
    #pragma unroll
    for (int kt = 0; kt < 8; ++kt) {
        #pragma unroll
        for (int s = 0; s < 4; ++s) {
            f16x8 v;
            #pragma unroll
            for (int j = 0; j < 8; ++j) {
                const int k = (kt << 5) + (q << 3) + j;   // 0..255
                const float w = (k < F) ? Wx[k * G + s * H + ncol]
                                        : Wh[(k - F) * G + s * H + ncol];
                v[j] = (_Float16)w;
            }
            bw[s][kt] = v;
        }
    }
    // bias folded into the exp2 argument:  sig(z+b) = rcp(1 + 2^(z*NLOG2E + nb))
    const float nbi = NLOG2E * bh[0 * H + ncol];
    const float nbf = NLOG2E * bh[1 * H + ncol];
    const float nbg = 2.0f * NLOG2E * bh[2 * H + ncol];
    const float nbo = NLOG2E * bh[3 * H + ncol];

    // ---- x staging: thread stages half-chunk (chunk = tid>>1, half = tid&1) ----
    const int xc = tid >> 1;              // chunk 0..255 (x half of K)
    const int xh = tid & 1;               // which f16x4 inside the chunk
    const int xm = xc & 15;               // batch row
    const int xk0 = ((xc >> 6) << 5) + (((xc >> 4) & 3) << 3) + (xh << 2); // k 0..124
    const float* pxbase = hin + (size_t)(r0 + xm) * T * F + xk0;

    // h-write indices (dword units into Abuf): lane pair (2a,2a+1) shares dwords.
    const int dimc = (wv << 4) + m16;     // this lane's h-dim (0..127)
    const int kk   = F + dimc;            // position of h in combined K
    const int hchunk = ((kk >> 5) << 6) + (((kk >> 3) & 3) << 4);
    const int a    = (m16 & 7) >> 1;      // dword inside chunk
    const int widx0 = (hchunk + (q << 2) + (p << 1)) * 4 + a;
    const int widx1 = widx0 + 4;

    // ---- stage x_0 and h_0 = 0 into Abuf[0] ----
    {
        const float4 x0 = *(const float4*)pxbase;
        f16x4 pk;
        pk[0] = (_Float16)x0.x; pk[1] = (_Float16)x0.y;
        pk[2] = (_Float16)x0.z; pk[3] = (_Float16)x0.w;
        *(f16x4*)((_Float16*)&Abuf[0][0] + xc * 8 + xh * 4) = pk;
        f16x4 zz = {};
        *(f16x4*)((_Float16*)&Abuf[0][0] + (256 + xc) * 8 + xh * 4) = zz;
    }

    f32x4 cst = {0.f, 0.f, 0.f, 0.f};   // cell state: rows q*4+g, dim dimc
    f32x4 hlast;

    __syncthreads();

    for (int t = 0; t < T; ++t) {
        // prefetch x_{t+1} (latency hidden under MFMA)
        const int tp = (t + 1 < T) ? t + 1 : T - 1;
        const float4 xn = *(const float4*)(pxbase + (size_t)tp * F);

        // ---- MFMA: z = [x_t, h] @ W  (bias folded into activation) ----
        const f16x8* Ab = &Abuf[t & 1][0];
        f32x4 z0 = {0.f, 0.f, 0.f, 0.f};
        f32x4 z1 = {0.f, 0.f, 0.f, 0.f};
        f32x4 z2 = {0.f, 0.f, 0.f, 0.f};
        f32x4 z3 = {0.f, 0.f, 0.f, 0.f};
        #pragma unroll
        for (int kt = 0; kt < 8; ++kt) {
            const f16x8 af = Ab[(kt << 6) + lane];
            z0 = __builtin_amdgcn_mfma_f32_16x16x32_f16(af, bw[0][kt], z0, 0, 0, 0);
            z1 = __builtin_amdgcn_mfma_f32_16x16x32_f16(af, bw[1][kt], z1, 0, 0, 0);
            z2 = __builtin_amdgcn_mfma_f32_16x16x32_f16(af, bw[2][kt], z2, 0, 0, 0);
            z3 = __builtin_amdgcn_mfma_f32_16x16x32_f16(af, bw[3][kt], z3, 0, 0, 0);
        }

        // ---- cell update, fully in-register (i,f,g,o all local to the lane) ----
        #pragma unroll
        for (int g = 0; g < 4; ++g) {
            const float iv = rcpf(1.0f + ex2(fmaf(z0[g], NLOG2E, nbi)));
            const float fv = rcpf(1.0f + ex2(fmaf(z1[g], NLOG2E, nbf)));
            const float gv = 2.0f * rcpf(1.0f + ex2(fmaf(z2[g], 2.0f * NLOG2E, nbg))) - 1.0f;
            const float ov = rcpf(1.0f + ex2(fmaf(z3[g], NLOG2E, nbo)));
            const float cn = fv * cst[g] + iv * gv;
            cst[g] = cn;
            const float th = 2.0f * rcpf(1.0f + ex2(cn * (2.0f * NLOG2E))) - 1.0f;
            hlast[g] = ov * th;
        }

        // ---- pack h with pair lane (via DPP quad_perm swap) -> 2x b32 writes ----
        uint32_t* An32 = (uint32_t*)&Abuf[(t + 1) & 1][0];
        uint32_t dd[4];
        #pragma unroll
        for (int g = 0; g < 4; ++g) {
            const float pp = dpp_swap1(hlast[g]);
            const float lo = p ? pp : hlast[g];
            const float hi = p ? hlast[g] : pp;
            dd[g] = __builtin_bit_cast(uint32_t, __builtin_amdgcn_cvt_pkrtz(lo, hi));
        }
        An32[widx0] = p ? dd[2] : dd[0];
        An32[widx1] = p ? dd[3] : dd[1];

        // ---- store prefetched x_{t+1} (chunk-linear, conflict-free b64) ----
        {
            f16x4 pk;
            pk[0] = (_Float16)xn.x; pk[1] = (_Float16)xn.y;
            pk[2] = (_Float16)xn.z; pk[3] = (_Float16)xn.w;
            *(f16x4*)((_Float16*)An32 + xc * 8 + xh * 4) = pk;
        }
        __syncthreads();
    }

    // ---- final hidden (fp32, pre-rounding) to LDS for the heads ----
    #pragma unroll
    for (int g = 0; g < 4; ++g) xf[(q << 2) + g][dimc] = hlast[g];
    __syncthreads();

    // ---- MLP heads (fp32 VALU; tiny FLOPs) ----
    const int n  = tid & 255;
    const int rh = tid >> 8;

    auto tanhl = [&](float x) { return 2.0f * rcpf(1.0f + ex2(x * (2.0f * NLOG2E))) - 1.0f; };

    auto layer = [&](const float* __restrict__ W, const float* __restrict__ bv,
                     const float* xin, int xs, int K, float* yout, int ys) {
        float acc[8];
        const float b = bv[n];
        #pragma unroll
        for (int r = 0; r < 8; ++r) acc[r] = b;
        #pragma unroll 4
        for (int k = 0; k < K; ++k) {
            const float w = W[k * 256 + n];
            #pragma unroll
            for (int r = 0; r < 8; ++r) acc[r] += xin[(rh * 8 + r) * xs + k] * w;
        }
        #pragma unroll
        for (int r = 0; r < 8; ++r) yout[(rh * 8 + r) * ys + n] = tanhl(acc[r]);
    };

    layer(Wa1, ba1, &xf[0][0], F + 1, 128, &hb[0][0][0], 257);   // actor L1
    __syncthreads();
    layer(Wa2, ba2, &hb[0][0][0], 257, 256, &hb[1][0][0], 257);  // actor L2
    __syncthreads();
    layer(Wc1, bc1, &xf[0][0], F + 1, 128, &hb[0][0][0], 257);   // critic L1
    if (tid < 128) {                                             // actor L3: mean + std
        const int r = tid >> 3, aa = tid & 7;
        float acc = ba3[aa];
        #pragma unroll 4
        for (int k = 0; k < 256; ++k) acc += hb[1][r][k] * Wa3[k * 8 + aa];
        out[(size_t)(r0 + r) * 17 + aa]     = acc;
        out[(size_t)(r0 + r) * 17 + 8 + aa] = __expf(logstd[aa]);
    }
    __syncthreads();
    layer(Wc2, bc2, &hb[0][0][0], 257, 256, &hb[1][0][0], 257);  // critic L2
    __syncthreads();
    if (tid < 16) {                                              // critic L3: value
        const int r = tid;
        float acc = bc3[0];
        #pragma unroll 4
        for (int k = 0; k < 256; ++k) acc += hb[1][r][k] * Wc3[k];
        out[(size_t)(r0 + r) * 17 + 16] = acc;
    }
}

extern "C" void kernel_launch(void* const* d_in, const int* in_sizes, int n_in,
                              void* d_out, int out_size, void* d_ws, size_t ws_size,
                              hipStream_t stream) {
    (void)in_sizes; (void)n_in; (void)d_ws; (void)ws_size; (void)out_size;
    const float* hin = (const float*)d_in[0];
    const float* Wx  = (const float*)d_in[1];
    const float* Wh  = (const float*)d_in[2];
    const float* bh  = (const float*)d_in[3];
    const float* Wa1 = (const float*)d_in[4];
    const float* ba1 = (const float*)d_in[5];
    const float* Wa2 = (const float*)d_in[6];
    const float* ba2 = (const float*)d_in[7];
    const float* Wa3 = (const float*)d_in[8];
    const float* ba3 = (const float*)d_in[9];
    const float* ls  = (const float*)d_in[10];
    const float* Wc1 = (const float*)d_in[11];
    const float* bc1 = (const float*)d_in[12];
    const float* Wc2 = (const float*)d_in[13];
    const float* bc2 = (const float*)d_in[14];
    const float* Wc3 = (const float*)d_in[15];
    const float* bc3 = (const float*)d_in[16];

    hipLaunchKernelGGL(ac_fused, dim3(64), dim3(512), 0, stream,
                       hin, Wx, Wh, bh, Wa1, ba1, Wa2, ba2, Wa3, ba3, ls,
                       Wc1, bc1, Wc2, bc2, Wc3, bc3, (float*)d_out);
}